// Round 1
// baseline (447.808 us; speedup 1.0000x reference)
//
#include <hip/hip_runtime.h>
#include <math.h>

#define D_MODEL 512
#define N_HEADS 8
#define DH      64
#define S_LEN   3072
#define BATCH   2
#define KMAX    32
#define M_ROWS  (BATCH * S_LEN)   // 6144

// ---------------------------------------------------------------------------
// GEMM: C[m][c_off + n] = sum_k A[m][k] * W[k][n] + bias[n]
// A: M x 512 (lda), W: 512 x 512 row-major, N = 512, K = 512.
// 64x64 tile, 256 threads, 4x4 micro-tile per thread.
// ---------------------------------------------------------------------------
__global__ __launch_bounds__(256) void gemm_bias_kernel(
    const float* __restrict__ A, int lda,
    const float* __restrict__ W,
    const float* __restrict__ bias,
    float* __restrict__ C, int ldc, int c_off)
{
    __shared__ __align__(16) float As[16][68];  // [k][m], stride 68 -> 272B rows (16B multiple)
    __shared__ __align__(16) float Bs[16][68];  // [k][n]

    const int tid = threadIdx.x;
    const int tx = tid & 15;          // micro-tile col group
    const int ty = tid >> 4;          // micro-tile row group
    const int m0 = blockIdx.x * 64;
    const int n0 = blockIdx.y * 64;

    float acc[4][4] = {};

    for (int kt = 0; kt < 512; kt += 16) {
        // Load A tile: 64 rows x 16 k. thread: k = tid&15, r = tid>>4 (+16*i)
        {
            const int k = tid & 15;
            const int r = tid >> 4;
            #pragma unroll
            for (int i = 0; i < 4; ++i) {
                As[k][r + i * 16] = A[(long)(m0 + r + i * 16) * lda + kt + k];
            }
        }
        // Load W tile: 16 k x 64 n. thread: n = tid&63, k = (tid>>6) + 4*i
        {
            const int n = tid & 63;
            const int k4 = tid >> 6;
            #pragma unroll
            for (int i = 0; i < 4; ++i) {
                const int k = k4 + i * 4;
                Bs[k][n] = W[(long)(kt + k) * 512 + n0 + n];
            }
        }
        __syncthreads();

        #pragma unroll
        for (int k = 0; k < 16; ++k) {
            float4 av = *reinterpret_cast<const float4*>(&As[k][ty * 4]);
            float4 bv = *reinterpret_cast<const float4*>(&Bs[k][tx * 4]);
            float a[4] = {av.x, av.y, av.z, av.w};
            float b[4] = {bv.x, bv.y, bv.z, bv.w};
            #pragma unroll
            for (int i = 0; i < 4; ++i)
                #pragma unroll
                for (int j = 0; j < 4; ++j)
                    acc[i][j] += a[i] * b[j];
        }
        __syncthreads();
    }

    #pragma unroll
    for (int i = 0; i < 4; ++i) {
        const int m = m0 + ty * 4 + i;
        #pragma unroll
        for (int j = 0; j < 4; ++j) {
            const int n = n0 + tx * 4 + j;
            C[(long)m * ldc + c_off + n] = acc[i][j] + bias[n];
        }
    }
}

// ---------------------------------------------------------------------------
// Top-k neighbor selection per row. One 256-thread block per (b, s).
// Replicates: stable argsort by dist (tie -> lower index), take 32, keep dist<0.5.
// ---------------------------------------------------------------------------
__global__ __launch_bounds__(256) void topk_kernel(
    const float* __restrict__ pos,   // B*S*3
    int* __restrict__ nbr_idx,       // B*S*KMAX
    int* __restrict__ nbr_cnt)       // B*S
{
    const int row = blockIdx.x;        // b*S + s
    const int b = row / S_LEN;
    const int tid = threadIdx.x;

    __shared__ unsigned long long s_wmin[4];
    __shared__ unsigned long long s_best;
    __shared__ int s_stop;
    __shared__ int s_sel[KMAX];

    const float px = pos[(long)row * 3 + 0];
    const float py = pos[(long)row * 3 + 1];
    const float pz = pos[(long)row * 3 + 2];
    const float* pb = pos + (long)b * S_LEN * 3;

    // 3072 / 256 = 12 candidates per thread, keys in registers.
    unsigned long long keys[12];
    #pragma unroll
    for (int i = 0; i < 12; ++i) {
        const int t = tid + i * 256;
        const float dx = px - pb[t * 3 + 0];
        const float dy = py - pb[t * 3 + 1];
        const float dz = pz - pb[t * 3 + 2];
        const float d2 = dx * dx + dy * dy + dz * dz;
        const float dist = sqrtf(d2);
        keys[i] = (((unsigned long long)__float_as_uint(dist)) << 32) | (unsigned int)t;
    }

    int cnt = 0;
    for (int it = 0; it < KMAX; ++it) {
        unsigned long long best = 0xFFFFFFFFFFFFFFFFULL;
        #pragma unroll
        for (int i = 0; i < 12; ++i) best = (keys[i] < best) ? keys[i] : best;
        #pragma unroll
        for (int off = 32; off; off >>= 1) {
            unsigned long long o = __shfl_xor(best, off, 64);
            best = (o < best) ? o : best;
        }
        if ((tid & 63) == 0) s_wmin[tid >> 6] = best;
        __syncthreads();
        if (tid == 0) {
            unsigned long long m = s_wmin[0];
            #pragma unroll
            for (int w = 1; w < 4; ++w) m = (s_wmin[w] < m) ? s_wmin[w] : m;
            const float dist = __uint_as_float((unsigned int)(m >> 32));
            if (dist < 0.5f) {
                s_sel[it] = (int)(m & 0xFFFFFFFFu);
                s_best = m;
                s_stop = 0;
            } else {
                s_stop = 1;
            }
        }
        __syncthreads();
        if (s_stop) break;
        const unsigned long long m = s_best;
        #pragma unroll
        for (int i = 0; i < 12; ++i)
            if (keys[i] == m) keys[i] = 0xFFFFFFFFFFFFFFFFULL;
        cnt = it + 1;
    }

    if (tid < KMAX) nbr_idx[(long)row * KMAX + tid] = (tid < cnt) ? s_sel[tid] : -1;
    if (tid == 0) nbr_cnt[row] = cnt;
}

// ---------------------------------------------------------------------------
// Sparse attention. One 512-thread block per (b, s); wave h handles head h.
// qkv layout: row-major (B*S) x 1536, [Q(512) | K(512) | V(512)].
// ---------------------------------------------------------------------------
__global__ __launch_bounds__(512) void attn_kernel(
    const float* __restrict__ qkv,
    const int* __restrict__ nbr_idx,
    const int* __restrict__ nbr_cnt,
    float* __restrict__ ao)          // (B*S) x 512
{
    const int row = blockIdx.x;
    const int b = row / S_LEN;
    const int tid = threadIdx.x;
    const int h = tid >> 6;
    const int lane = tid & 63;

    __shared__ int s_nbr[KMAX];
    __shared__ int s_cnt;
    __shared__ __align__(16) float sQ[N_HEADS][DH];
    __shared__ float sW[N_HEADS][KMAX];

    if (tid < KMAX) s_nbr[tid] = nbr_idx[(long)row * KMAX + tid];
    if (tid == 0) s_cnt = nbr_cnt[row];
    sQ[h][lane] = qkv[(long)row * 1536 + tid];
    __syncthreads();
    const int cnt = s_cnt;

    // --- scores: lane pair (j, j+32): half-dot over 32 dims each ---
    const int j = lane & 31;
    const int half = lane >> 5;
    float partial = 0.f;
    if (j < cnt) {
        const int t = s_nbr[j];
        const float* kp = qkv + (long)(b * S_LEN + t) * 1536 + 512 + h * DH + half * 32;
        const float* qp = &sQ[h][half * 32];
        #pragma unroll
        for (int d = 0; d < 32; d += 4) {
            const float4 kv = *reinterpret_cast<const float4*>(kp + d);
            partial += qp[d] * kv.x + qp[d + 1] * kv.y + qp[d + 2] * kv.z + qp[d + 3] * kv.w;
        }
    }
    partial += __shfl_down(partial, 32, 64);  // combine halves into lanes 0..31

    float score = (half == 0 && j < cnt) ? partial * 0.125f : -INFINITY;

    // softmax over lanes 0..31 of this wave
    float m = score;
    #pragma unroll
    for (int off = 16; off; off >>= 1) m = fmaxf(m, __shfl_xor(m, off, 64));
    if (half == 0) {
        const float p = (j < cnt) ? expf(score - m) : 0.f;
        float sum = p;
        #pragma unroll
        for (int off = 16; off; off >>= 1) sum += __shfl_xor(sum, off, 64);
        sW[h][j] = p / sum;   // cnt >= 1 always (self), sum > 0
    }
    __syncthreads();

    // --- PV: lane d accumulates over neighbors, coalesced V reads ---
    float o = 0.f;
    for (int jj = 0; jj < cnt; ++jj) {
        const int t = s_nbr[jj];
        o += sW[h][jj] * qkv[(long)(b * S_LEN + t) * 1536 + 1024 + h * DH + lane];
    }
    ao[(long)row * D_MODEL + tid] = o;
}

// ---------------------------------------------------------------------------
extern "C" void kernel_launch(void* const* d_in, const int* in_sizes, int n_in,
                              void* d_out, int out_size, void* d_ws, size_t ws_size,
                              hipStream_t stream) {
    const float* x   = (const float*)d_in[0];
    const float* pos = (const float*)d_in[1];
    const float* Wq  = (const float*)d_in[2];
    const float* bq  = (const float*)d_in[3];
    const float* Wk  = (const float*)d_in[4];
    const float* bk  = (const float*)d_in[5];
    const float* Wv  = (const float*)d_in[6];
    const float* bv  = (const float*)d_in[7];
    const float* Wo  = (const float*)d_in[8];
    const float* bo  = (const float*)d_in[9];
    float* out = (float*)d_out;

    float* qkv = (float*)d_ws;                           // M_ROWS x 1536
    float* ao  = qkv + (size_t)M_ROWS * 1536;            // M_ROWS x 512
    int*   nidx = (int*)(ao + (size_t)M_ROWS * D_MODEL); // M_ROWS x 32
    int*   ncnt = nidx + (size_t)M_ROWS * KMAX;          // M_ROWS

    dim3 blk(256);
    dim3 grid(M_ROWS / 64, D_MODEL / 64);

    gemm_bias_kernel<<<grid, blk, 0, stream>>>(x, D_MODEL, Wq, bq, qkv, 1536, 0);
    gemm_bias_kernel<<<grid, blk, 0, stream>>>(x, D_MODEL, Wk, bk, qkv, 1536, 512);
    gemm_bias_kernel<<<grid, blk, 0, stream>>>(x, D_MODEL, Wv, bv, qkv, 1536, 1024);

    topk_kernel<<<M_ROWS, 256, 0, stream>>>(pos, nidx, ncnt);

    attn_kernel<<<M_ROWS, 512, 0, stream>>>(qkv, nidx, ncnt, ao);

    gemm_bias_kernel<<<grid, blk, 0, stream>>>(ao, D_MODEL, Wo, bo, out, D_MODEL, 0);
}

// Round 2
// 298.898 us; speedup vs baseline: 1.4982x; 1.4982x over previous
//
#include <hip/hip_runtime.h>
#include <math.h>

#define D_MODEL 512
#define N_HEADS 8
#define DH      64
#define S_LEN   3072
#define BATCH   2
#define KMAX    32
#define M_ROWS  (BATCH * S_LEN)   // 6144
#define CAND_CAP 512              // max radius-filtered candidates per row (expected max ~150)

// ---------------------------------------------------------------------------
// GEMM: C[m][c_off + n] = sum_k A[m][k] * W[k][n] + bias[n]
// A: M x 512 (lda), W: 512 x 512 row-major, N = 512, K = 512.
// 64x64 tile, 256 threads, 4x4 micro-tile per thread.
// ---------------------------------------------------------------------------
__global__ __launch_bounds__(256) void gemm_bias_kernel(
    const float* __restrict__ A, int lda,
    const float* __restrict__ W,
    const float* __restrict__ bias,
    float* __restrict__ C, int ldc, int c_off)
{
    __shared__ __align__(16) float As[16][68];  // [k][m], stride 68 -> 272B rows (16B multiple)
    __shared__ __align__(16) float Bs[16][68];  // [k][n]

    const int tid = threadIdx.x;
    const int tx = tid & 15;          // micro-tile col group
    const int ty = tid >> 4;          // micro-tile row group
    const int m0 = blockIdx.x * 64;
    const int n0 = blockIdx.y * 64;

    float acc[4][4] = {};

    for (int kt = 0; kt < 512; kt += 16) {
        // Load A tile: 64 rows x 16 k. thread: k = tid&15, r = tid>>4 (+16*i)
        {
            const int k = tid & 15;
            const int r = tid >> 4;
            #pragma unroll
            for (int i = 0; i < 4; ++i) {
                As[k][r + i * 16] = A[(long)(m0 + r + i * 16) * lda + kt + k];
            }
        }
        // Load W tile: 16 k x 64 n. thread: n = tid&63, k = (tid>>6) + 4*i
        {
            const int n = tid & 63;
            const int k4 = tid >> 6;
            #pragma unroll
            for (int i = 0; i < 4; ++i) {
                const int k = k4 + i * 4;
                Bs[k][n] = W[(long)(kt + k) * 512 + n0 + n];
            }
        }
        __syncthreads();

        #pragma unroll
        for (int k = 0; k < 16; ++k) {
            float4 av = *reinterpret_cast<const float4*>(&As[k][ty * 4]);
            float4 bv = *reinterpret_cast<const float4*>(&Bs[k][tx * 4]);
            float a[4] = {av.x, av.y, av.z, av.w};
            float b[4] = {bv.x, bv.y, bv.z, bv.w};
            #pragma unroll
            for (int i = 0; i < 4; ++i)
                #pragma unroll
                for (int j = 0; j < 4; ++j)
                    acc[i][j] += a[i] * b[j];
        }
        __syncthreads();
    }

    #pragma unroll
    for (int i = 0; i < 4; ++i) {
        const int m = m0 + ty * 4 + i;
        #pragma unroll
        for (int j = 0; j < 4; ++j) {
            const int n = n0 + tx * 4 + j;
            C[(long)m * ldc + c_off + n] = acc[i][j] + bias[n];
        }
    }
}

// ---------------------------------------------------------------------------
// Top-k neighbor selection per row, rank-based. One 256-thread block per (b,s).
// Phase 1: radius filter (dist < 0.5), compact survivors' keys into LDS.
// Phase 2: rank = #{smaller keys}; rank < 32 -> selected (order-free set,
//          identical selection semantics to iterative argmin: key is
//          dist_bits<<32 | idx, stable tie-break by index).
// ---------------------------------------------------------------------------
__global__ __launch_bounds__(256) void topk_kernel(
    const float* __restrict__ pos,   // B*S*3
    int* __restrict__ nbr_idx,       // B*S*KMAX
    int* __restrict__ nbr_cnt)       // B*S
{
    const int row = blockIdx.x;        // b*S + s
    const int b = row / S_LEN;
    const int tid = threadIdx.x;

    __shared__ unsigned long long s_keys[CAND_CAP];
    __shared__ int s_n;

    if (tid == 0) s_n = 0;
    __syncthreads();

    const float px = pos[(long)row * 3 + 0];
    const float py = pos[(long)row * 3 + 1];
    const float pz = pos[(long)row * 3 + 2];
    const float* pb = pos + (long)b * S_LEN * 3;

    // 3072 / 256 = 12 candidates per thread. Same arithmetic as the verified
    // iterative version (sqrtf on d2, compare dist < 0.5f) -> identical set.
    #pragma unroll
    for (int i = 0; i < 12; ++i) {
        const int t = tid + i * 256;
        const float dx = px - pb[t * 3 + 0];
        const float dy = py - pb[t * 3 + 1];
        const float dz = pz - pb[t * 3 + 2];
        const float d2 = dx * dx + dy * dy + dz * dz;
        const float dist = sqrtf(d2);
        if (dist < 0.5f) {
            const int slot = atomicAdd(&s_n, 1);
            if (slot < CAND_CAP)
                s_keys[slot] = (((unsigned long long)__float_as_uint(dist)) << 32)
                               | (unsigned int)t;
        }
    }
    __syncthreads();

    const int n = (s_n < CAND_CAP) ? s_n : CAND_CAP;

    // Rank selection: keys are unique (index in low bits), so ranks are a
    // perfect permutation; rank < KMAX writes land in distinct slots.
    for (int c = tid; c < n; c += 256) {
        const unsigned long long mykey = s_keys[c];
        int rank = 0;
        for (int j = 0; j < n; ++j)
            rank += (s_keys[j] < mykey) ? 1 : 0;
        if (rank < KMAX)
            nbr_idx[(long)row * KMAX + rank] = (int)(mykey & 0xFFFFFFFFu);
    }
    if (tid == 0) nbr_cnt[row] = (n < KMAX) ? n : KMAX;
}

// ---------------------------------------------------------------------------
// Sparse attention. One 512-thread block per (b, s); wave h handles head h.
// qkv layout: row-major (B*S) x 1536, [Q(512) | K(512) | V(512)].
// ---------------------------------------------------------------------------
__global__ __launch_bounds__(512) void attn_kernel(
    const float* __restrict__ qkv,
    const int* __restrict__ nbr_idx,
    const int* __restrict__ nbr_cnt,
    float* __restrict__ ao)          // (B*S) x 512
{
    const int row = blockIdx.x;
    const int b = row / S_LEN;
    const int tid = threadIdx.x;
    const int h = tid >> 6;
    const int lane = tid & 63;

    __shared__ int s_nbr[KMAX];
    __shared__ int s_cnt;
    __shared__ __align__(16) float sQ[N_HEADS][DH];
    __shared__ float sW[N_HEADS][KMAX];

    if (tid < KMAX) s_nbr[tid] = nbr_idx[(long)row * KMAX + tid];
    if (tid == 0) s_cnt = nbr_cnt[row];
    sQ[h][lane] = qkv[(long)row * 1536 + tid];
    __syncthreads();
    const int cnt = s_cnt;

    // --- scores: lane pair (j, j+32): half-dot over 32 dims each ---
    const int j = lane & 31;
    const int half = lane >> 5;
    float partial = 0.f;
    if (j < cnt) {
        const int t = s_nbr[j];
        const float* kp = qkv + (long)(b * S_LEN + t) * 1536 + 512 + h * DH + half * 32;
        const float* qp = &sQ[h][half * 32];
        #pragma unroll
        for (int d = 0; d < 32; d += 4) {
            const float4 kv = *reinterpret_cast<const float4*>(kp + d);
            partial += qp[d] * kv.x + qp[d + 1] * kv.y + qp[d + 2] * kv.z + qp[d + 3] * kv.w;
        }
    }
    partial += __shfl_down(partial, 32, 64);  // combine halves into lanes 0..31

    float score = (half == 0 && j < cnt) ? partial * 0.125f : -INFINITY;

    // softmax over lanes 0..31 of this wave
    float m = score;
    #pragma unroll
    for (int off = 16; off; off >>= 1) m = fmaxf(m, __shfl_xor(m, off, 64));
    if (half == 0) {
        const float p = (j < cnt) ? expf(score - m) : 0.f;
        float sum = p;
        #pragma unroll
        for (int off = 16; off; off >>= 1) sum += __shfl_xor(sum, off, 64);
        sW[h][j] = p / sum;   // cnt >= 1 always (self), sum > 0
    }
    __syncthreads();

    // --- PV: lane d accumulates over neighbors, coalesced V reads ---
    float o = 0.f;
    for (int jj = 0; jj < cnt; ++jj) {
        const int t = s_nbr[jj];
        o += sW[h][jj] * qkv[(long)(b * S_LEN + t) * 1536 + 1024 + h * DH + lane];
    }
    ao[(long)row * D_MODEL + tid] = o;
}

// ---------------------------------------------------------------------------
extern "C" void kernel_launch(void* const* d_in, const int* in_sizes, int n_in,
                              void* d_out, int out_size, void* d_ws, size_t ws_size,
                              hipStream_t stream) {
    const float* x   = (const float*)d_in[0];
    const float* pos = (const float*)d_in[1];
    const float* Wq  = (const float*)d_in[2];
    const float* bq  = (const float*)d_in[3];
    const float* Wk  = (const float*)d_in[4];
    const float* bk  = (const float*)d_in[5];
    const float* Wv  = (const float*)d_in[6];
    const float* bv  = (const float*)d_in[7];
    const float* Wo  = (const float*)d_in[8];
    const float* bo  = (const float*)d_in[9];
    float* out = (float*)d_out;

    float* qkv = (float*)d_ws;                           // M_ROWS x 1536
    float* ao  = qkv + (size_t)M_ROWS * 1536;            // M_ROWS x 512
    int*   nidx = (int*)(ao + (size_t)M_ROWS * D_MODEL); // M_ROWS x 32
    int*   ncnt = nidx + (size_t)M_ROWS * KMAX;          // M_ROWS

    dim3 blk(256);
    dim3 grid(M_ROWS / 64, D_MODEL / 64);

    gemm_bias_kernel<<<grid, blk, 0, stream>>>(x, D_MODEL, Wq, bq, qkv, 1536, 0);
    gemm_bias_kernel<<<grid, blk, 0, stream>>>(x, D_MODEL, Wk, bk, qkv, 1536, 512);
    gemm_bias_kernel<<<grid, blk, 0, stream>>>(x, D_MODEL, Wv, bv, qkv, 1536, 1024);

    topk_kernel<<<M_ROWS, 256, 0, stream>>>(pos, nidx, ncnt);

    attn_kernel<<<M_ROWS, 512, 0, stream>>>(qkv, nidx, ncnt, ao);

    gemm_bias_kernel<<<grid, blk, 0, stream>>>(ao, D_MODEL, Wo, bo, out, D_MODEL, 0);
}

// Round 3
// 116.020 us; speedup vs baseline: 3.8597x; 2.5763x over previous
//
#include <hip/hip_runtime.h>
#include <math.h>

#define D_MODEL 512
#define N_HEADS 8
#define DH      64
#define S_LEN   3072
#define BATCH   2
#define KMAX    32
#define M_ROWS  (BATCH * S_LEN)   // 6144
#define CAND_CAP 512

typedef __attribute__((ext_vector_type(8))) short bf16x8;
typedef __attribute__((ext_vector_type(4))) float f32x4;

__device__ __forceinline__ float b2f(unsigned int u) {
    return __uint_as_float((u & 0xFFFFu) << 16);
}
__device__ __forceinline__ unsigned short f2b(float f) {
    unsigned int u = __float_as_uint(f);
    return (unsigned short)((u + 0x7FFFu + ((u >> 16) & 1u)) >> 16);  // RNE
}

// ---------------------------------------------------------------------------
// x (fp32, M x 512) -> bf16
// ---------------------------------------------------------------------------
__global__ __launch_bounds__(256) void conv_x_kernel(
    const float* __restrict__ x, unsigned short* __restrict__ xb)
{
    const int i = (blockIdx.x * 256 + threadIdx.x) * 4;
    const float4 v = *reinterpret_cast<const float4*>(x + i);
    ushort4 o;
    o.x = f2b(v.x); o.y = f2b(v.y); o.z = f2b(v.z); o.w = f2b(v.w);
    *reinterpret_cast<ushort4*>(xb + i) = o;
}

// ---------------------------------------------------------------------------
// Pack weights: Wt[n][k] = W*[k][n'] as bf16, n = 0..2047
//   [0,512) Wq | [512,1024) Wk | [1024,1536) Wv | [1536,2048) Wo
// Also pack bqkv[0..1536). Scatter reads are L2-resident (1 MB matrices).
// ---------------------------------------------------------------------------
__global__ __launch_bounds__(256) void pack_w_kernel(
    const float* __restrict__ Wq, const float* __restrict__ bq,
    const float* __restrict__ Wk, const float* __restrict__ bk,
    const float* __restrict__ Wv, const float* __restrict__ bv,
    const float* __restrict__ Wo,
    unsigned short* __restrict__ Wt, float* __restrict__ bqkv)
{
    const int n = blockIdx.x;
    const float* W; int nn;
    if (n < 512)       { W = Wq; nn = n; }
    else if (n < 1024) { W = Wk; nn = n - 512; }
    else if (n < 1536) { W = Wv; nn = n - 1024; }
    else               { W = Wo; nn = n - 1536; }
    for (int k = threadIdx.x; k < 512; k += 256)
        Wt[(size_t)n * 512 + k] = f2b(W[(size_t)k * 512 + nn]);
    if (threadIdx.x == 0 && n < 1536) {
        const float* bsel = (n < 512) ? bq : (n < 1024) ? bk : bv;
        bqkv[n] = bsel[nn];
    }
}

// ---------------------------------------------------------------------------
// bf16 MFMA GEMM: C[m][n] = sum_k A[m][k] * Bt[n][k] + bias[n]
// A: M x 512 bf16 row-major. Bt: N x 512 bf16 row-major (pre-transposed W).
// 128x128 tile, 256 threads (4 waves 2x2, each 64x64), BK=32,
// global_load_lds width-16 staging, mfma_f32_16x16x32_bf16.
// ---------------------------------------------------------------------------
template <bool OUT_BF16>
__global__ __launch_bounds__(256) void gemm_mfma_kernel(
    const unsigned short* __restrict__ A,
    const unsigned short* __restrict__ Bt,
    const float* __restrict__ bias,
    void* __restrict__ Cv, int ldc)
{
    constexpr int K = 512;
    __shared__ __align__(16) unsigned short As[128 * 32];
    __shared__ __align__(16) unsigned short Bs[128 * 32];

    const int tid = threadIdx.x;
    const int m0 = blockIdx.x * 128;
    const int n0 = blockIdx.y * 128;
    const int wid = tid >> 6;
    const int lane = tid & 63;
    const int wm = (wid >> 1) * 64;
    const int wn = (wid & 1) * 64;
    const int l15 = lane & 15;
    const int kg = lane >> 4;

    const int srow = tid >> 2;          // 0..63 (chunk-relative row)
    const int sk = (tid & 3) * 8;       // k element offset

    f32x4 acc[4][4] = {};

    for (int kt = 0; kt < K; kt += 32) {
        #pragma unroll
        for (int c = 0; c < 2; ++c) {
            const unsigned short* ga = A + (size_t)(m0 + c * 64 + srow) * K + kt + sk;
            __builtin_amdgcn_global_load_lds(
                (const __attribute__((address_space(1))) void*)ga,
                (__attribute__((address_space(3))) void*)(&As[c * 2048 + tid * 8]),
                16, 0, 0);
            const unsigned short* gb = Bt + (size_t)(n0 + c * 64 + srow) * K + kt + sk;
            __builtin_amdgcn_global_load_lds(
                (const __attribute__((address_space(1))) void*)gb,
                (__attribute__((address_space(3))) void*)(&Bs[c * 2048 + tid * 8]),
                16, 0, 0);
        }
        __syncthreads();

        bf16x8 af[4], bfr[4];
        #pragma unroll
        for (int i = 0; i < 4; ++i) {
            af[i]  = *reinterpret_cast<const bf16x8*>(&As[(wm + i * 16 + l15) * 32 + kg * 8]);
            bfr[i] = *reinterpret_cast<const bf16x8*>(&Bs[(wn + i * 16 + l15) * 32 + kg * 8]);
        }
        #pragma unroll
        for (int i = 0; i < 4; ++i)
            #pragma unroll
            for (int j = 0; j < 4; ++j)
                acc[i][j] = __builtin_amdgcn_mfma_f32_16x16x32_bf16(af[i], bfr[j], acc[i][j], 0, 0, 0);
        __syncthreads();
    }

    // C/D layout (m89-verified): col = lane&15, row = (lane>>4)*4 + reg
    const int crow = kg * 4;
    #pragma unroll
    for (int i = 0; i < 4; ++i) {
        #pragma unroll
        for (int j = 0; j < 4; ++j) {
            const int col = n0 + wn + j * 16 + l15;
            const float bb = bias[col];
            #pragma unroll
            for (int r = 0; r < 4; ++r) {
                const int row = m0 + wm + i * 16 + crow + r;
                const float v = acc[i][j][r] + bb;
                if (OUT_BF16)
                    ((unsigned short*)Cv)[(size_t)row * ldc + col] = f2b(v);
                else
                    ((float*)Cv)[(size_t)row * ldc + col] = v;
            }
        }
    }
}

// ---------------------------------------------------------------------------
// Top-k neighbor selection (rank-based), one 256-thread block per row.
// ---------------------------------------------------------------------------
__global__ __launch_bounds__(256) void topk_kernel(
    const float* __restrict__ pos,
    int* __restrict__ nbr_idx,
    int* __restrict__ nbr_cnt)
{
    const int row = blockIdx.x;
    const int b = row / S_LEN;
    const int tid = threadIdx.x;

    __shared__ unsigned long long s_keys[CAND_CAP];
    __shared__ int s_n;

    if (tid == 0) s_n = 0;
    __syncthreads();

    const float px = pos[(long)row * 3 + 0];
    const float py = pos[(long)row * 3 + 1];
    const float pz = pos[(long)row * 3 + 2];
    const float* pb = pos + (long)b * S_LEN * 3;

    #pragma unroll
    for (int i = 0; i < 12; ++i) {
        const int t = tid + i * 256;
        const float dx = px - pb[t * 3 + 0];
        const float dy = py - pb[t * 3 + 1];
        const float dz = pz - pb[t * 3 + 2];
        const float dist = sqrtf(dx * dx + dy * dy + dz * dz);
        if (dist < 0.5f) {
            const int slot = atomicAdd(&s_n, 1);
            if (slot < CAND_CAP)
                s_keys[slot] = (((unsigned long long)__float_as_uint(dist)) << 32)
                               | (unsigned int)t;
        }
    }
    __syncthreads();

    const int n = (s_n < CAND_CAP) ? s_n : CAND_CAP;

    for (int c = tid; c < n; c += 256) {
        const unsigned long long mykey = s_keys[c];
        int rank = 0;
        for (int j = 0; j < n; ++j)
            rank += (s_keys[j] < mykey) ? 1 : 0;
        if (rank < KMAX)
            nbr_idx[(long)row * KMAX + rank] = (int)(mykey & 0xFFFFFFFFu);
    }
    if (tid == 0) nbr_cnt[row] = (n < KMAX) ? n : KMAX;
}

// ---------------------------------------------------------------------------
// Sparse attention, bf16 qkv in / bf16 ao out. One 512-thread block per row.
// qkv: [M][1536] bf16 = [Q512 | K512 | V512].
// ---------------------------------------------------------------------------
__global__ __launch_bounds__(512) void attn_kernel(
    const unsigned short* __restrict__ qkv,
    const int* __restrict__ nbr_idx,
    const int* __restrict__ nbr_cnt,
    unsigned short* __restrict__ ao)
{
    const int row = blockIdx.x;
    const int b = row / S_LEN;
    const int tid = threadIdx.x;
    const int h = tid >> 6;
    const int lane = tid & 63;

    __shared__ int s_nbr[KMAX];
    __shared__ int s_cnt;
    __shared__ float sQ[N_HEADS][DH];
    __shared__ float sW[N_HEADS][KMAX];

    if (tid < KMAX) s_nbr[tid] = nbr_idx[(size_t)row * KMAX + tid];
    if (tid == 0) s_cnt = nbr_cnt[row];
    sQ[h][lane] = b2f(qkv[(size_t)row * 1536 + tid]);
    __syncthreads();
    const int cnt = s_cnt;

    // --- scores: lane pair (j, j+32) splits the 64-dim dot ---
    const int j = lane & 31;
    const int half = lane >> 5;
    float partial = 0.f;
    if (j < cnt) {
        const int t = s_nbr[j];
        const unsigned short* kp = qkv + (size_t)(b * S_LEN + t) * 1536 + 512 + h * DH + half * 32;
        const float* qp = &sQ[h][half * 32];
        #pragma unroll
        for (int d0 = 0; d0 < 32; d0 += 8) {
            const uint4 u = *reinterpret_cast<const uint4*>(kp + d0);
            partial += qp[d0 + 0] * b2f(u.x) + qp[d0 + 1] * b2f(u.x >> 16)
                     + qp[d0 + 2] * b2f(u.y) + qp[d0 + 3] * b2f(u.y >> 16)
                     + qp[d0 + 4] * b2f(u.z) + qp[d0 + 5] * b2f(u.z >> 16)
                     + qp[d0 + 6] * b2f(u.w) + qp[d0 + 7] * b2f(u.w >> 16);
        }
    }
    partial += __shfl_down(partial, 32, 64);

    const float score = (half == 0 && j < cnt) ? partial * 0.125f : -INFINITY;

    float m = score;
    #pragma unroll
    for (int off = 16; off; off >>= 1) m = fmaxf(m, __shfl_xor(m, off, 64));
    if (half == 0) {
        const float p = (j < cnt) ? expf(score - m) : 0.f;
        float sum = p;
        #pragma unroll
        for (int off = 16; off; off >>= 1) sum += __shfl_xor(sum, off, 64);
        sW[h][j] = p / sum;
    }
    __syncthreads();

    // --- PV: unrolled x4 for MLP (4 independent loads in flight) ---
    const unsigned short* vbase = qkv + 1024 + h * DH + lane;
    float o = 0.f;
    int jj = 0;
    for (; jj + 4 <= cnt; jj += 4) {
        const int t0 = s_nbr[jj], t1 = s_nbr[jj + 1], t2 = s_nbr[jj + 2], t3 = s_nbr[jj + 3];
        const float v0 = b2f(vbase[(size_t)(b * S_LEN + t0) * 1536]);
        const float v1 = b2f(vbase[(size_t)(b * S_LEN + t1) * 1536]);
        const float v2 = b2f(vbase[(size_t)(b * S_LEN + t2) * 1536]);
        const float v3 = b2f(vbase[(size_t)(b * S_LEN + t3) * 1536]);
        o += sW[h][jj] * v0 + sW[h][jj + 1] * v1 + sW[h][jj + 2] * v2 + sW[h][jj + 3] * v3;
    }
    for (; jj < cnt; ++jj)
        o += sW[h][jj] * b2f(vbase[(size_t)(b * S_LEN + s_nbr[jj]) * 1536]);

    ao[(size_t)row * D_MODEL + tid] = f2b(o);
}

// ---------------------------------------------------------------------------
extern "C" void kernel_launch(void* const* d_in, const int* in_sizes, int n_in,
                              void* d_out, int out_size, void* d_ws, size_t ws_size,
                              hipStream_t stream) {
    const float* x   = (const float*)d_in[0];
    const float* pos = (const float*)d_in[1];
    const float* Wq  = (const float*)d_in[2];
    const float* bq  = (const float*)d_in[3];
    const float* Wk  = (const float*)d_in[4];
    const float* bk  = (const float*)d_in[5];
    const float* Wv  = (const float*)d_in[6];
    const float* bv  = (const float*)d_in[7];
    const float* Wo  = (const float*)d_in[8];
    const float* bo  = (const float*)d_in[9];
    float* out = (float*)d_out;

    // workspace layout (all 16B-aligned)
    unsigned short* xb   = (unsigned short*)d_ws;                 // 6144*512
    unsigned short* Wt   = xb + (size_t)M_ROWS * 512;             // 2048*512
    float*          bqkv = (float*)(Wt + (size_t)2048 * 512);     // 1536
    unsigned short* qkvb = (unsigned short*)(bqkv + 1536);        // 6144*1536
    unsigned short* aob  = qkvb + (size_t)M_ROWS * 1536;          // 6144*512
    int*            nidx = (int*)(aob + (size_t)M_ROWS * 512);    // 6144*32
    int*            ncnt = nidx + (size_t)M_ROWS * KMAX;          // 6144

    conv_x_kernel<<<M_ROWS * D_MODEL / (256 * 4), 256, 0, stream>>>(x, xb);
    pack_w_kernel<<<2048, 256, 0, stream>>>(Wq, bq, Wk, bk, Wv, bv, Wo, Wt, bqkv);
    topk_kernel<<<M_ROWS, 256, 0, stream>>>(pos, nidx, ncnt);

    dim3 g1(M_ROWS / 128, 1536 / 128);
    gemm_mfma_kernel<true><<<g1, 256, 0, stream>>>(xb, Wt, bqkv, qkvb, 1536);

    attn_kernel<<<M_ROWS, 512, 0, stream>>>(qkvb, nidx, ncnt, aob);

    dim3 g2(M_ROWS / 128, 512 / 128);
    gemm_mfma_kernel<false><<<g2, 256, 0, stream>>>(aob, Wt + (size_t)1536 * 512, bo, out, 512);
}